// Round 3
// baseline (395.946 us; speedup 1.0000x reference)
//
#include <hip/hip_runtime.h>
#include <hip/hip_bf16.h>

// Problem constants
#define B_  4
#define S_  1024
#define H_  1024
#define NH  16
#define HD  64
#define P_  4

typedef __attribute__((ext_vector_type(8))) short bf16x8;
typedef __attribute__((ext_vector_type(4))) float f32x4;
typedef __attribute__((ext_vector_type(16))) float f32x16;
typedef __attribute__((ext_vector_type(4))) unsigned int u32x4;

__device__ __forceinline__ float b2f(short s) {
  union { unsigned int u; float f; } v;
  v.u = ((unsigned int)(unsigned short)s) << 16;
  return v.f;
}
__device__ __forceinline__ short f2b(float f) {
  __hip_bfloat16 h = __float2bfloat16(f);
  return *reinterpret_cast<short*>(&h);
}
// raw v_exp_f32: returns 2^x
__device__ __forceinline__ float fast_exp2(float x) {
  float r;
  asm volatile("v_exp_f32 %0, %1" : "=v"(r) : "v"(x));
  return r;
}
// async global->LDS, 16B per lane. LDS dest = wave-uniform base + lane*16.
__device__ __forceinline__ void gload_lds16(const void* g, void* l) {
  __builtin_amdgcn_global_load_lds(
      (const __attribute__((address_space(1))) unsigned int*)((uintptr_t)g),
      (__attribute__((address_space(3))) unsigned int*)((uintptr_t)l),
      16, 0, 0);
}

// ---------------------------------------------------------------------------
// prep: fused cast(hidden), cast(prev), 4x weight transpose->bf16, rope table,
// pooled mean. grid 14480, block 256. Branch is block-uniform.
__global__ void prep_kernel(const float* __restrict__ hidden, const float* __restrict__ prev,
                            const float* __restrict__ wq, const float* __restrict__ wk,
                            const float* __restrict__ wv, const float* __restrict__ wo,
                            short* __restrict__ hbf, short* __restrict__ pbf,
                            short* __restrict__ wqT, short* __restrict__ wkT,
                            short* __restrict__ wvT, short* __restrict__ woT,
                            float* __restrict__ cost, float* __restrict__ sint,
                            float* __restrict__ pooled) {
  __shared__ short tile[32][33];
  int bid = blockIdx.x, tid = threadIdx.x;
  if (bid < 10240) {  // casts
    const float* src; short* dst; int idx;
    if (bid < 2048) { src = hidden; dst = hbf; idx = bid * 256 + tid; }
    else            { src = prev;   dst = pbf; idx = (bid - 2048) * 256 + tid; }
    const float4* s4 = (const float4*)(src + (size_t)idx * 8);
    float4 a = s4[0], b = s4[1];
    bf16x8 pk;
    pk[0] = f2b(a.x); pk[1] = f2b(a.y); pk[2] = f2b(a.z); pk[3] = f2b(a.w);
    pk[4] = f2b(b.x); pk[5] = f2b(b.y); pk[6] = f2b(b.z); pk[7] = f2b(b.w);
    *(bf16x8*)(dst + (size_t)idx * 8) = pk;
  } else if (bid < 14336) {  // weight transposes
    int tb = bid - 10240;
    int z = tb >> 10, t = tb & 1023;
    const float* src = (z == 0) ? wq : (z == 1) ? wk : (z == 2) ? wv : wo;
    short*       dst = (z == 0) ? wqT : (z == 1) ? wkT : (z == 2) ? wvT : woT;
    int tx = tid & 31, ty = tid >> 5;
    int c0 = (t & 31) * 32, r0 = (t >> 5) * 32;
#pragma unroll
    for (int i = 0; i < 4; ++i)
      tile[ty + 8 * i][tx] = f2b(src[(r0 + ty + 8 * i) * 1024 + c0 + tx]);
    __syncthreads();
#pragma unroll
    for (int i = 0; i < 4; ++i)
      dst[(c0 + ty + 8 * i) * 1024 + r0 + tx] = tile[tx][ty + 8 * i];
  } else if (bid < 14464) {  // rope table
    int idx = (bid - 14336) * 256 + tid;
    int s = idx >> 5, i = idx & 31;
    float invf = expf(-(float)i * (logf(10000.0f) / 32.0f));
    float a = (float)s * invf;
    cost[idx] = cosf(a);
    sint[idx] = sinf(a);
  } else {  // pooled
    int idx = (bid - 14464) * 256 + tid;
    int b = idx >> 10, e = idx & 1023;
    const float* hp = hidden + (size_t)b * S_ * H_ + e;
    float s = 0.f;
    for (int t = 0; t < S_; ++t) s += hp[t * H_];
    pooled[idx] = s * (1.0f / 1024.0f);
  }
}

// ---------------------------------------------------------------------------
__global__ void gate_kernel(const float* __restrict__ pooled, const float* __restrict__ wg,
                            float* __restrict__ lw) {
  int w = threadIdx.x >> 6, lane = threadIdx.x & 63;
  float a0 = 0.f, a1 = 0.f, a2 = 0.f, a3 = 0.f;
  for (int e = lane; e < 1024; e += 64) {
    float pv = pooled[w * 1024 + e];
    a0 += pv * wg[e * 4 + 0];
    a1 += pv * wg[e * 4 + 1];
    a2 += pv * wg[e * 4 + 2];
    a3 += pv * wg[e * 4 + 3];
  }
#pragma unroll
  for (int off = 32; off > 0; off >>= 1) {
    a0 += __shfl_xor(a0, off, 64);
    a1 += __shfl_xor(a1, off, 64);
    a2 += __shfl_xor(a2, off, 64);
    a3 += __shfl_xor(a3, off, 64);
  }
  if (lane == 0) {
    float mx = fmaxf(fmaxf(a0, a1), fmaxf(a2, a3));
    float e0 = expf(a0 - mx), e1 = expf(a1 - mx), e2 = expf(a2 - mx), e3 = expf(a3 - mx);
    float inv = 1.0f / (e0 + e1 + e2 + e3);
    lw[w * 4 + 0] = e0 * inv;
    lw[w * 4 + 1] = e1 * inv;
    lw[w * 4 + 2] = e2 * inv;
    lw[w * 4 + 3] = e3 * inv;
  }
}

// ---------------------------------------------------------------------------
// QKV projections, 8-phase 256^2 pipelined GEMM (T2+T3+T4+T5).
// Unfused: block regions Q[0,64) K[64,320) V[320,576). 512 thr = 8 waves
// (2M x 4N), wave tile 128x64 interleaved across LDS halves:
//   mt 0-3 -> Alo (rows wm*64+..), mt 4-7 -> Ahi (128 + wm*64+..)
//   nt 0-1 -> Blo (d<32 of head), nt 2-3 -> Bhi (d>=32)  [rope pairing in-reg]
// LDS 128KB: 2 buf x (A 256x64 + B 256x64). Stage order Alo,Blo,Bhi,Ahi;
// vmcnt(4) at ph0/ph1/ph2 publishes exactly the half-tiles read that phase;
// 4-6 loads stay in flight across raw s_barriers (never drained in-loop).
__launch_bounds__(512, 2)
__global__ void qkv_gemm(const short* __restrict__ hbf, const short* __restrict__ pbf,
                         const short* __restrict__ BTq, const short* __restrict__ BTk,
                         const short* __restrict__ BTv,
                         const float* __restrict__ bq, const float* __restrict__ bk,
                         const float* __restrict__ bv,
                         short* __restrict__ outq, short* __restrict__ outk,
                         short* __restrict__ outv,
                         const float* __restrict__ cost, const float* __restrict__ sint) {
  __shared__ __align__(16) short As[2][2][8192];  // [buf][half][128*64]
  __shared__ __align__(16) short Bs[2][2][8192];

  int id = blockIdx.x;
  int wg = (id & 7) * 72 + (id >> 3);   // bijective XCD swizzle (576 = 8*72)
  int matrix, mt_, nt_;
  if (wg < 64)       { matrix = 0; int l = wg;       mt_ = l >> 2; nt_ = l & 3; }
  else if (wg < 320) { matrix = 1; int l = wg - 64;  mt_ = l >> 2; nt_ = l & 3; }
  else               { matrix = 2; int l = wg - 320; mt_ = l >> 2; nt_ = l & 3; }
  int m0 = mt_ * 256, n0 = nt_ * 256;
  const short* A  = (matrix == 0) ? hbf : pbf;
  const short* BT = (matrix == 0) ? BTq : (matrix == 1) ? BTk : BTv;
  const short* Ab = A + (size_t)m0 * 1024;
  const short* Bb = BT + (size_t)n0 * 1024;

  int tid = threadIdx.x;
  int lane = tid & 63, wv = tid >> 6;
  int quad = lane >> 4, c = lane & 15;
  int wm = wv >> 2, wn = wv & 3;

  f32x4 acc[8][4] = {};
  bf16x8 afr[4][2], bfr[4][2];

  // staging address precompute (2 rounds of 512 threads per 128x64 half-tile)
  int r0row = tid >> 3,        r0ch = tid & 7;
  int r1row = (512 + tid) >> 3, r1ch = tid & 7;  // li=512+tid -> row 64..127, ch same
  // A half h: src row = h*128 + row; B half h: src n = (bl>>5)*64 + h*32 + (bl&31)
  int b0n = (r0row >> 5) * 64 + (r0row & 31);
  int b1n = (r1row >> 5) * 64 + (r1row & 31);
  int a0c = (r0ch ^ (r0row & 7)) * 8;
  int a1c = (r1ch ^ (r1row & 7)) * 8;

#define STAGE_A(buf, h, k0s) do {                                              \
    gload_lds16(Ab + (size_t)((h)*128 + r0row) * 1024 + (k0s) + a0c,           \
                &As[buf][h][tid * 8]);                                         \
    gload_lds16(Ab + (size_t)((h)*128 + r1row) * 1024 + (k0s) + a1c,           \
                &As[buf][h][(512 + tid) * 8]);                                 \
  } while (0)
#define STAGE_B(buf, h, k0s) do {                                              \
    gload_lds16(Bb + (size_t)(b0n + (h)*32) * 1024 + (k0s) + a0c,              \
                &Bs[buf][h][tid * 8]);                                         \
    gload_lds16(Bb + (size_t)(b1n + (h)*32) * 1024 + (k0s) + a1c,              \
                &Bs[buf][h][(512 + tid) * 8]);                                 \
  } while (0)
#define PIPE_SYNC4() do {                                                      \
    asm volatile("s_waitcnt vmcnt(4)" ::: "memory");                           \
    __builtin_amdgcn_s_barrier();                                              \
    __builtin_amdgcn_sched_barrier(0);                                         \
  } while (0)

  // prologue: stage tile 0 into buf 0 in publish order Alo, Blo, Bhi, Ahi
  STAGE_A(0, 0, 0);
  STAGE_B(0, 0, 0);
  STAGE_B(0, 1, 0);
  STAGE_A(0, 1, 0);

#pragma unroll 1
  for (int t = 0; t < 16; ++t) {
    int cur = t & 1, nc = cur ^ 1;
    int k0 = t * 64;
    int kn = (t < 15) ? k0 + 64 : k0;  // last iter: redundant re-stage (keeps vmcnt uniform)

    // ---- phase 0: publish Alo+Blo; compute acc[0..3][0..1]
    PIPE_SYNC4();
#pragma unroll
    for (int i = 0; i < 4; ++i) {
      int row = wm * 64 + i * 16 + c;
      const short* base = &As[cur][0][row * 64];
#pragma unroll
      for (int ko = 0; ko < 2; ++ko)
        afr[i][ko] = *(const bf16x8*)&base[(((ko * 4 + quad) ^ (row & 7)) * 8)];
    }
#pragma unroll
    for (int nt = 0; nt < 2; ++nt) {
      int bl = wn * 32 + nt * 16 + c;
      const short* base = &Bs[cur][0][bl * 64];
#pragma unroll
      for (int ko = 0; ko < 2; ++ko)
        bfr[nt][ko] = *(const bf16x8*)&base[(((ko * 4 + quad) ^ (bl & 7)) * 8)];
    }
    STAGE_A(nc, 0, kn);
    __builtin_amdgcn_s_setprio(1);
#pragma unroll
    for (int i = 0; i < 4; ++i)
#pragma unroll
      for (int nt = 0; nt < 2; ++nt)
#pragma unroll
        for (int ko = 0; ko < 2; ++ko)
          acc[i][nt] = __builtin_amdgcn_mfma_f32_16x16x32_bf16(afr[i][ko], bfr[nt][ko], acc[i][nt], 0, 0, 0);
    __builtin_amdgcn_s_setprio(0);

    // ---- phase 1: publish Bhi; compute acc[0..3][2..3]
    PIPE_SYNC4();
#pragma unroll
    for (int nt = 2; nt < 4; ++nt) {
      int bl = wn * 32 + (nt & 1) * 16 + c;
      const short* base = &Bs[cur][1][bl * 64];
#pragma unroll
      for (int ko = 0; ko < 2; ++ko)
        bfr[nt][ko] = *(const bf16x8*)&base[(((ko * 4 + quad) ^ (bl & 7)) * 8)];
    }
    STAGE_B(nc, 0, kn);
    __builtin_amdgcn_s_setprio(1);
#pragma unroll
    for (int i = 0; i < 4; ++i)
#pragma unroll
      for (int nt = 2; nt < 4; ++nt)
#pragma unroll
        for (int ko = 0; ko < 2; ++ko)
          acc[i][nt] = __builtin_amdgcn_mfma_f32_16x16x32_bf16(afr[i][ko], bfr[nt][ko], acc[i][nt], 0, 0, 0);
    __builtin_amdgcn_s_setprio(0);

    // ---- phase 2: publish Ahi; compute acc[4..7][2..3]
    PIPE_SYNC4();
#pragma unroll
    for (int i = 0; i < 4; ++i) {
      int row = wm * 64 + i * 16 + c;
      const short* base = &As[cur][1][row * 64];
#pragma unroll
      for (int ko = 0; ko < 2; ++ko)
        afr[i][ko] = *(const bf16x8*)&base[(((ko * 4 + quad) ^ (row & 7)) * 8)];
    }
    STAGE_B(nc, 1, kn);
    __builtin_amdgcn_s_setprio(1);
#pragma unroll
    for (int i = 0; i < 4; ++i)
#pragma unroll
      for (int nt = 2; nt < 4; ++nt)
#pragma unroll
        for (int ko = 0; ko < 2; ++ko)
          acc[4 + i][nt] = __builtin_amdgcn_mfma_f32_16x16x32_bf16(afr[i][ko], bfr[nt][ko], acc[4 + i][nt], 0, 0, 0);
    __builtin_amdgcn_s_setprio(0);

    // ---- phase 3: no new reads; compute acc[4..7][0..1]
    STAGE_A(nc, 1, kn);
    __builtin_amdgcn_s_setprio(1);
#pragma unroll
    for (int i = 0; i < 4; ++i)
#pragma unroll
      for (int nt = 0; nt < 2; ++nt)
#pragma unroll
        for (int ko = 0; ko < 2; ++ko)
          acc[4 + i][nt] = __builtin_amdgcn_mfma_f32_16x16x32_bf16(afr[i][ko], bfr[nt][ko], acc[4 + i][nt], 0, 0, 0);
    __builtin_amdgcn_s_setprio(0);
  }
#undef STAGE_A
#undef STAGE_B
#undef PIPE_SYNC4

  // drain the final redundant re-stage before epilogue / kernel end
  asm volatile("s_waitcnt vmcnt(0)" ::: "memory");

  // Epilogue. acc[mt][nt]: row gm = m0 + (mt>>2)*128 + wm*64 + (mt&3)*16 + quad*4 + j
  //                        col d  = (nt>>1)*32 + (nt&1)*16 + c, head hh = n0/64 + wn
  int hh = (n0 >> 6) + wn;
  if (matrix <= 1) {
    const float* bias = (matrix == 0) ? bq : bk;
    short* outp = (matrix == 0) ? outq : outk;
    float b0 = bias[hh * 64 + c];
    float b1 = bias[hh * 64 + 16 + c];
    float b2_ = bias[hh * 64 + 32 + c];
    float b3 = bias[hh * 64 + 48 + c];
#pragma unroll
    for (int mt = 0; mt < 8; ++mt) {
      int gmb = m0 + (mt >> 2) * 128 + wm * 64 + (mt & 3) * 16 + quad * 4;
#pragma unroll
      for (int j = 0; j < 4; ++j) {
        int m = gmb + j;
        int s = m & 1023;
        int bbx = m >> 10;
        size_t orow = ((size_t)(bbx * NH + hh) * S_ + s) * HD;
        float c0f = cost[s * 32 + c], s0f = sint[s * 32 + c];
        float x1 = acc[mt][0][j] + b0, x2 = acc[mt][2][j] + b2_;
        outp[orow + c]      = f2b(x1 * c0f - x2 * s0f);
        outp[orow + 32 + c] = f2b(x1 * s0f + x2 * c0f);
        float c1f = cost[s * 32 + 16 + c], s1f = sint[s * 32 + 16 + c];
        float y1 = acc[mt][1][j] + b1, y2 = acc[mt][3][j] + b3;
        outp[orow + 16 + c] = f2b(y1 * c1f - y2 * s1f);
        outp[orow + 48 + c] = f2b(y1 * s1f + y2 * c1f);
      }
    }
  } else {
    float bb[4];
#pragma unroll
    for (int nt = 0; nt < 4; ++nt) bb[nt] = bv[hh * 64 + (nt >> 1) * 32 + (nt & 1) * 16 + c];
#pragma unroll
    for (int mt = 0; mt < 8; ++mt) {
      int gmb = m0 + (mt >> 2) * 128 + wm * 64 + (mt & 3) * 16 + quad * 4;
      int s4 = gmb & 1023, pb = gmb >> 10;
#pragma unroll
      for (int nt = 0; nt < 4; ++nt) {
        int d = (nt >> 1) * 32 + (nt & 1) * 16 + c;
        ushort4 pk;
        pk.x = (unsigned short)f2b(acc[mt][nt][0] + bb[nt]);
        pk.y = (unsigned short)f2b(acc[mt][nt][1] + bb[nt]);
        pk.z = (unsigned short)f2b(acc[mt][nt][2] + bb[nt]);
        pk.w = (unsigned short)f2b(acc[mt][nt][3] + bb[nt]);
        *(ushort4*)&outv[(((size_t)pb * NH + hh) * HD + d) * S_ + s4] = pk;
      }
    }
  }
}

// ---------------------------------------------------------------------------
// Flash attention v4: 32x32x16 MFMA, S^T = K*Q^T formulation, P kept fully
// in registers via v_cvt_pk_bf16_f32 + v_permlane32_swap_b32 (no P LDS
// round-trip). 128 q-rows/block (wave owns 32), 64 keys/iter,
// no-max softmax. grid 2048: blk = g*64 + qt*8 + x, pbh = g*8 + x.
__launch_bounds__(256, 4)
__global__ void attn_kernel(const short* __restrict__ q, const short* __restrict__ k,
                            const short* __restrict__ vt, short* __restrict__ o) {
  int blk = blockIdx.x;
  int x = blk & 7, qt = (blk >> 3) & 7, g = blk >> 6;
  int pbh = g * 8 + x;
  int b = (pbh >> 4) & 3, h = pbh & 15;
  int tid = threadIdx.x;
  int w = tid >> 6, lane = tid & 63;
  int l31 = lane & 31, hh = lane >> 5;   // half index (lane>=32)
  int r7 = l31 & 7;

  __shared__ __align__(16) short Klds[64 * 64];
  __shared__ __align__(16) short Vlds[64 * 64];
  __shared__ float lsumf[4][32];

  // Q fragments (B operand of 32x32x16): lane holds Q[q=l31][hd=step*16+hh*8+j]
  const short* qbase = q + ((size_t)(b * NH + h) * S_ + qt * 128 + w * 32 + l31) * HD + hh * 8;
  bf16x8 aq[4];
#pragma unroll
  for (int st4 = 0; st4 < 4; ++st4) aq[st4] = *(const bf16x8*)(qbase + st4 * 16);

  const short* kb = k + (size_t)pbh * S_ * HD;
  const short* vb = vt + (size_t)pbh * HD * S_;

  f32x16 O0 = {}, O1 = {};
  float ls0 = 0.f, ls1 = 0.f, ls2 = 0.f, ls3 = 0.f;
  const float cs = 0.18033688011f;  // 0.125 * log2(e)

  int sr = tid >> 3;
  int lc = (tid & 7) ^ (sr & 7);

  for (int kt = 0; kt < 16; ++kt) {
    __syncthreads();
    const short* ksrc = kb + (kt * 64 + sr) * HD + lc * 8;
    gload_lds16(ksrc,           Klds + tid * 8);
    gload_lds16(ksrc + 32 * HD, Klds + 2048 + tid * 8);
    const short* vsrc = vb + (size_t)sr * S_ + kt * 64 + lc * 8;
    gload_lds16(vsrc,           Vlds + tid * 8);
    gload_lds16(vsrc + 32 * S_, Vlds + 2048 + tid * 8);
    __syncthreads();

    // QK^T: two 32x32 k-tiles; contraction over hd=64 in 4 steps of 16.
    // S^T reg layout: q = l31, k32 = (r&3)+8*(r>>2)+4*hh.
    u32x4 pa[4];
#pragma unroll
    for (int tau = 0; tau < 2; ++tau) {
      f32x16 st = {};
#pragma unroll
      for (int step = 0; step < 4; ++step) {
        bf16x8 kf = *(const bf16x8*)&Klds[(tau * 32 + l31) * 64 + (((step * 2 + hh) ^ r7) * 8)];
        st = __builtin_amdgcn_mfma_f32_32x32x16_bf16(kf, aq[step], st, 0, 0, 0);
      }
      unsigned wb[8];
#pragma unroll
      for (int m = 0; m < 8; ++m) {
        float p0 = fast_exp2(st[2 * m] * cs);
        float p1 = fast_exp2(st[2 * m + 1] * cs);
        float ps = p0 + p1;
        if ((m & 3) == 0) ls0 += ps;
        else if ((m & 3) == 1) ls1 += ps;
        else if ((m & 3) == 2) ls2 += ps;
        else ls3 += ps;
        asm("v_cvt_pk_bf16_f32 %0, %1, %2" : "=v"(wb[m]) : "v"(p0), "v"(p1));
      }
#pragma unroll
      for (int gg = 0; gg < 2; ++gg) {
        unsigned x0 = wb[4 * gg + 0], y0 = wb[4 * gg + 2];
        unsigned x1 = wb[4 * gg + 1], y1 = wb[4 * gg + 3];
        asm volatile("v_permlane32_swap_b32 %0, %1" : "+v"(x0), "+v"(y0));
        asm volatile("v_permlane32_swap_b32 %0, %1" : "+v"(x1), "+v"(y1));
        u32x4 paw;
        paw[0] = x0; paw[1] = x1; paw[2] = y0; paw[3] = y1;
        pa[2 * tau + gg] = paw;
      }
    }

    // PV: O[q][d], two 32-wide d-tiles, contraction k=64 in 4 steps of 16.
#pragma unroll
    for (int T = 0; T < 4; ++T) {
      bf16x8 ap = __builtin_bit_cast(bf16x8, pa[T]);
      bf16x8 vf0 = *(const bf16x8*)&Vlds[l31 * 64 + (((T * 2 + hh) ^ r7) * 8)];
      O0 = __builtin_amdgcn_mfma_f32_32x32x16_bf16(ap, vf0, O0, 0, 0, 0);
      bf16x8 vf1 = *(const bf16x8*)&Vlds[(32 + l31) * 64 + (((T * 2 + hh) ^ r7) * 8)];
      O1 = __builtin_amdgcn_mfma_f32_32x32x16_bf16(ap, vf1, O1, 0, 0, 0);
    }
  }

  float lsum = (ls0 + ls1) + (ls2 + ls3);
  lsum += __shfl_xor(lsum, 32, 64);
  if (lane < 32) lsumf[w][l31] = lsum;

  short* ob = o + ((size_t)pbh * S_ + qt * 128 + w * 32) * HD;
#pragma unroll
  for (int gg = 0; gg < 4; ++gg) {
    f32x4 lv = *(const f32x4*)&lsumf[w][4 * hh + 8 * gg];
#pragma unroll
    for (int j = 0; j < 4; ++j) {
      float inv = 1.0f / lv[j];
      int qrow = 4 * hh + 8 * gg + j;
      ob[qrow * HD + l31]      = f2b(O0[4 * gg + j] * inv);
      ob[qrow * HD + 32 + l31] = f2b(O1[4 * gg + j] * inv);
    }
  }
}

// ---------------------------------------------------------------------------
__global__ void combine_kernel(const short* __restrict__ o, const float* __restrict__ lw,
                               short* __restrict__ comb) {
  int idx = blockIdx.x * 256 + threadIdx.x;
  int e8 = idx & 127;
  int s = (idx >> 7) & 1023;
  int b = idx >> 17;
  int h = e8 >> 3, d0 = (e8 & 7) * 8;
  float acc[8] = {};
#pragma unroll
  for (int p = 0; p < 4; ++p) {
    float wgt = lw[p * 4 + b];  // faithful transposed broadcast: LW[p][b]
    const short* op = o + (((size_t)(p * 4 + b) * NH + h) * S_ + s) * HD + d0;
    bf16x8 v = *(const bf16x8*)op;
#pragma unroll
    for (int i = 0; i < 8; ++i) acc[i] += wgt * b2f(v[i]);
  }
  bf16x8 pk;
#pragma unroll
  for (int i = 0; i < 8; ++i) pk[i] = f2b(acc[i]);
  *(bf16x8*)&comb[((size_t)b * S_ + s) * H_ + e8 * 8] = pk;
}

// ---------------------------------------------------------------------------
// Final projection: C[4096,1024] fp32 = comb @ woT + bo. 64x128 tiles, BK=64,
// swizzled LDS, XCD-coherent decode. grid 512 linear, (256,4).
__launch_bounds__(256, 4)
__global__ void gemm_out(const short* __restrict__ A, const short* __restrict__ BT,
                         const float* __restrict__ bias, float* __restrict__ outf) {
  __shared__ __align__(16) short As[64 * 64];
  __shared__ __align__(16) short Bs[128 * 64];
  int id = blockIdx.x;
  int xcd = id & 7;
  int local = id >> 3;        // 0..63
  int n0i = local & 7;
  int yl = local >> 3;        // 0..7
  int y = yl * 8 + xcd;       // 0..63
  int tid = threadIdx.x;
  int lane = tid & 63, wvv = tid >> 6;
  int quad = lane >> 4, c = lane & 15;
  int wm = wvv & 1, wn = wvv >> 1;
  int m0 = y * 64, n0 = n0i * 128;
  f32x4 acc[2][4] = {};
  const short* Ab = A + (size_t)m0 * 1024;
  const short* Bb = BT + (size_t)n0 * 1024;
  int sr = tid >> 3, sch = tid & 7;

  for (int kb = 0; kb < 16; ++kb) {
    int k0 = kb * 64;
    __syncthreads();
#pragma unroll
    for (int rd = 0; rd < 2; ++rd) {
      int row = sr + rd * 32;
      int col = ((sch ^ (row & 7)) * 8) + k0;
      gload_lds16(Ab + row * 1024 + col, As + rd * 2048 + tid * 8);
    }
#pragma unroll
    for (int rd = 0; rd < 4; ++rd) {
      int row = sr + rd * 32;
      int col = ((sch ^ (row & 7)) * 8) + k0;
      gload_lds16(Bb + row * 1024 + col, Bs + rd * 2048 + tid * 8);
    }
    __syncthreads();
#pragma unroll
    for (int ko = 0; ko < 2; ++ko) {
      bf16x8 af[2], bfr[4];
#pragma unroll
      for (int mt = 0; mt < 2; ++mt) {
        int row = wm * 32 + mt * 16 + c;
        af[mt] = *(const bf16x8*)&As[row * 64 + (((ko * 4 + quad) ^ (row & 7)) * 8)];
      }
#pragma unroll
      for (int nt = 0; nt < 4; ++nt) {
        int row = wn * 64 + nt * 16 + c;
        bfr[nt] = *(const bf16x8*)&Bs[row * 64 + (((ko * 4 + quad) ^ (row & 7)) * 8)];
      }
#pragma unroll
      for (int mt = 0; mt < 2; ++mt)
#pragma unroll
        for (int nt = 0; nt < 4; ++nt)
          acc[mt][nt] = __builtin_amdgcn_mfma_f32_16x16x32_bf16(af[mt], bfr[nt], acc[mt][nt], 0, 0, 0);
    }
  }

  int colb = n0 + wn * 64;
  float bb[4];
#pragma unroll
  for (int nt = 0; nt < 4; ++nt) bb[nt] = bias[colb + nt * 16 + c];
#pragma unroll
  for (int mt = 0; mt < 2; ++mt) {
    int gm = m0 + wm * 32 + mt * 16 + quad * 4;
#pragma unroll
    for (int j = 0; j < 4; ++j) {
      int m = gm + j;
#pragma unroll
      for (int nt = 0; nt < 4; ++nt)
        outf[(size_t)m * 1024 + colb + nt * 16 + c] = acc[mt][nt][j] + bb[nt];
    }
  }
}

// ---------------------------------------------------------------------------
extern "C" void kernel_launch(void* const* d_in, const int* in_sizes, int n_in,
                              void* d_out, int out_size, void* d_ws, size_t ws_size,
                              hipStream_t stream) {
  (void)in_sizes; (void)n_in; (void)out_size; (void)ws_size;
  const float* hidden = (const float*)d_in[0];
  const float* prev   = (const float*)d_in[1];
  const float* wq = (const float*)d_in[2];
  const float* bq = (const float*)d_in[3];
  const float* wk = (const float*)d_in[4];
  const float* bk = (const float*)d_in[5];
  const float* wv = (const float*)d_in[6];
  const float* bv = (const float*)d_in[7];
  const float* wo = (const float*)d_in[8];
  const float* bo = (const float*)d_in[9];
  const float* wg = (const float*)d_in[10];
  float* out = (float*)d_out;
  char* ws = (char*)d_ws;

  size_t off = 0;
  short* wqT = (short*)(ws + off); off += (size_t)1024 * 1024 * 2;
  short* wkT = (short*)(ws + off); off += (size_t)1024 * 1024 * 2;
  short* wvT = (short*)(ws + off); off += (size_t)1024 * 1024 * 2;
  short* woT = (short*)(ws + off); off += (size_t)1024 * 1024 * 2;
  short* hbf = (short*)(ws + off); off += (size_t)B_ * S_ * H_ * 2;
  short* pbf = (short*)(ws + off); off += (size_t)P_ * B_ * S_ * H_ * 2;
  short* qbf = (short*)(ws + off); off += (size_t)B_ * S_ * H_ * 2;
  short* kbf = (short*)(ws + off); off += (size_t)P_ * B_ * S_ * H_ * 2;
  short* vtb = (short*)(ws + off); off += (size_t)P_ * B_ * S_ * H_ * 2;
  float* cost = (float*)(ws + off); off += (size_t)S_ * 32 * 4;
  float* sint = (float*)(ws + off); off += (size_t)S_ * 32 * 4;
  float* pooled = (float*)(ws + off); off += (size_t)B_ * H_ * 4;
  float* lw = (float*)(ws + off); off += 64;
  short* obf  = pbf;  // alias: pbf dead after QKV proj
  short* comb = qbf;  // alias: qbf dead after attention

  prep_kernel<<<14480, 256, 0, stream>>>(hidden, prev, wq, wk, wv, wo,
                                         hbf, pbf, wqT, wkT, wvT, woT,
                                         cost, sint, pooled);
  gate_kernel<<<1, 256, 0, stream>>>(pooled, wg, lw);
  qkv_gemm<<<576, 512, 0, stream>>>(hbf, pbf, wqT, wkT, wvT,
                                    bq, bk, bv, qbf, kbf, vtb, cost, sint);
  attn_kernel<<<2048, 256, 0, stream>>>(qbf, kbf, vtb, obf);
  combine_kernel<<<2048, 256, 0, stream>>>(obf, lw, comb);
  gemm_out<<<512, 256, 0, stream>>>(comb, woT, bo, out);
}

// Round 4
// 347.996 us; speedup vs baseline: 1.1378x; 1.1378x over previous
//
#include <hip/hip_runtime.h>
#include <hip/hip_bf16.h>

// Problem constants
#define B_  4
#define S_  1024
#define H_  1024
#define NH  16
#define HD  64
#define P_  4

typedef __attribute__((ext_vector_type(8))) short bf16x8;
typedef __attribute__((ext_vector_type(4))) float f32x4;
typedef __attribute__((ext_vector_type(16))) float f32x16;
typedef __attribute__((ext_vector_type(4))) unsigned int u32x4;

__device__ __forceinline__ float b2f(short s) {
  union { unsigned int u; float f; } v;
  v.u = ((unsigned int)(unsigned short)s) << 16;
  return v.f;
}
__device__ __forceinline__ short f2b(float f) {
  __hip_bfloat16 h = __float2bfloat16(f);
  return *reinterpret_cast<short*>(&h);
}
// raw v_exp_f32: returns 2^x
__device__ __forceinline__ float fast_exp2(float x) {
  float r;
  asm volatile("v_exp_f32 %0, %1" : "=v"(r) : "v"(x));
  return r;
}
// async global->LDS, 16B per lane. LDS dest = wave-uniform base + lane*16.
__device__ __forceinline__ void gload_lds16(const void* g, void* l) {
  __builtin_amdgcn_global_load_lds(
      (const __attribute__((address_space(1))) unsigned int*)((uintptr_t)g),
      (__attribute__((address_space(3))) unsigned int*)((uintptr_t)l),
      16, 0, 0);
}

// ---------------------------------------------------------------------------
// prep: fused cast(hidden), cast(prev), 4x weight transpose->bf16, rope table,
// pooled partial means (128 blocks, float4). grid 14592, block 256.
__global__ void prep_kernel(const float* __restrict__ hidden, const float* __restrict__ prev,
                            const float* __restrict__ wq, const float* __restrict__ wk,
                            const float* __restrict__ wv, const float* __restrict__ wo,
                            short* __restrict__ hbf, short* __restrict__ pbf,
                            short* __restrict__ wqT, short* __restrict__ wkT,
                            short* __restrict__ wvT, short* __restrict__ woT,
                            float* __restrict__ cost, float* __restrict__ sint,
                            float* __restrict__ pooled) {
  __shared__ short tile[32][33];
  int bid = blockIdx.x, tid = threadIdx.x;
  if (bid < 10240) {  // casts
    const float* src; short* dst; int idx;
    if (bid < 2048) { src = hidden; dst = hbf; idx = bid * 256 + tid; }
    else            { src = prev;   dst = pbf; idx = (bid - 2048) * 256 + tid; }
    const float4* s4 = (const float4*)(src + (size_t)idx * 8);
    float4 a = s4[0], b = s4[1];
    bf16x8 pk;
    pk[0] = f2b(a.x); pk[1] = f2b(a.y); pk[2] = f2b(a.z); pk[3] = f2b(a.w);
    pk[4] = f2b(b.x); pk[5] = f2b(b.y); pk[6] = f2b(b.z); pk[7] = f2b(b.w);
    *(bf16x8*)(dst + (size_t)idx * 8) = pk;
  } else if (bid < 14336) {  // weight transposes
    int tb = bid - 10240;
    int z = tb >> 10, t = tb & 1023;
    const float* src = (z == 0) ? wq : (z == 1) ? wk : (z == 2) ? wv : wo;
    short*       dst = (z == 0) ? wqT : (z == 1) ? wkT : (z == 2) ? wvT : woT;
    int tx = tid & 31, ty = tid >> 5;
    int c0 = (t & 31) * 32, r0 = (t >> 5) * 32;
#pragma unroll
    for (int i = 0; i < 4; ++i)
      tile[ty + 8 * i][tx] = f2b(src[(r0 + ty + 8 * i) * 1024 + c0 + tx]);
    __syncthreads();
#pragma unroll
    for (int i = 0; i < 4; ++i)
      dst[(c0 + ty + 8 * i) * 1024 + r0 + tx] = tile[tx][ty + 8 * i];
  } else if (bid < 14464) {  // rope table
    int idx = (bid - 14336) * 256 + tid;
    int s = idx >> 5, i = idx & 31;
    float invf = expf(-(float)i * (logf(10000.0f) / 32.0f));
    float a = (float)s * invf;
    cost[idx] = cosf(a);
    sint[idx] = sinf(a);
  } else {  // pooled partials: 128 blocks = (b 0..3) x (chunk 0..31), 32 rows each
    int idx = bid - 14464;
    int b = idx >> 5, chunk = idx & 31;
    const float* hp = hidden + (size_t)b * S_ * H_ + (size_t)chunk * 32 * H_ + tid * 4;
    float4 s = {0.f, 0.f, 0.f, 0.f};
#pragma unroll 4
    for (int t = 0; t < 32; ++t) {
      float4 v = *(const float4*)(hp + (size_t)t * H_);
      s.x += v.x; s.y += v.y; s.z += v.z; s.w += v.w;
    }
    float4 r;
    r.x = s.x * (1.0f / 1024.0f); r.y = s.y * (1.0f / 1024.0f);
    r.z = s.z * (1.0f / 1024.0f); r.w = s.w * (1.0f / 1024.0f);
    *(float4*)(pooled + (size_t)(b * 32 + chunk) * 1024 + tid * 4) = r;
  }
}

// ---------------------------------------------------------------------------
// gate: sums the 32 pooled partials per (b,e), then softmax(pooled @ wg).
__global__ void gate_kernel(const float* __restrict__ pooled, const float* __restrict__ wg,
                            float* __restrict__ lw) {
  int w = threadIdx.x >> 6, lane = threadIdx.x & 63;
  float a0 = 0.f, a1 = 0.f, a2 = 0.f, a3 = 0.f;
  for (int e = lane; e < 1024; e += 64) {
    float pv = 0.f;
#pragma unroll
    for (int ch = 0; ch < 32; ++ch) pv += pooled[(size_t)(w * 32 + ch) * 1024 + e];
    a0 += pv * wg[e * 4 + 0];
    a1 += pv * wg[e * 4 + 1];
    a2 += pv * wg[e * 4 + 2];
    a3 += pv * wg[e * 4 + 3];
  }
#pragma unroll
  for (int off = 32; off > 0; off >>= 1) {
    a0 += __shfl_xor(a0, off, 64);
    a1 += __shfl_xor(a1, off, 64);
    a2 += __shfl_xor(a2, off, 64);
    a3 += __shfl_xor(a3, off, 64);
  }
  if (lane == 0) {
    float mx = fmaxf(fmaxf(a0, a1), fmaxf(a2, a3));
    float e0 = expf(a0 - mx), e1 = expf(a1 - mx), e2 = expf(a2 - mx), e3 = expf(a3 - mx);
    float inv = 1.0f / (e0 + e1 + e2 + e3);
    lw[w * 4 + 0] = e0 * inv;
    lw[w * 4 + 1] = e1 * inv;
    lw[w * 4 + 2] = e2 * inv;
    lw[w * 4 + 3] = e3 * inv;
  }
}

// ---------------------------------------------------------------------------
// bias + RoPE epilogue -> [blk*NH+hh][s][64] bf16
__device__ __forceinline__ void rope_epilogue(const f32x4 (&acc)[4][4], const float* __restrict__ bias,
                                              short* __restrict__ outp,
                                              const float* __restrict__ cost,
                                              const float* __restrict__ sint,
                                              int m0, int wm, int quad, int c, int hh) {
  float b0 = bias[hh * 64 + c];
  float b1 = bias[hh * 64 + 16 + c];
  float b2_ = bias[hh * 64 + 32 + c];
  float b3 = bias[hh * 64 + 48 + c];
#pragma unroll
  for (int mt = 0; mt < 4; ++mt) {
    int gm = m0 + wm * 64 + mt * 16 + quad * 4;
#pragma unroll
    for (int j = 0; j < 4; ++j) {
      int m = gm + j;
      int s = m & 1023;
      int bbx = m >> 10;
      int orow = ((bbx * NH + hh) * S_ + s) * HD;
      float c0f = cost[s * 32 + c], s0f = sint[s * 32 + c];
      float x1 = acc[mt][0][j] + b0, x2 = acc[mt][2][j] + b2_;
      outp[orow + c]      = f2b(x1 * c0f - x2 * s0f);
      outp[orow + 32 + c] = f2b(x1 * s0f + x2 * c0f);
      float c1f = cost[s * 32 + 16 + c], s1f = sint[s * 32 + 16 + c];
      float y1 = acc[mt][1][j] + b1, y2 = acc[mt][3][j] + b3;
      outp[orow + 16 + c] = f2b(y1 * c1f - y2 * s1f);
      outp[orow + 48 + c] = f2b(y1 * s1f + y2 * c1f);
    }
  }
}

// ---------------------------------------------------------------------------
// Fused Q+K+V projections. Linear grid 1280; decode keeps the 8 n-blocks of
// each A-row-tile consecutive on ONE XCD (A-tile stays hot in that L2), and
// spreads Q/KV rows evenly across XCDs. 128x128 tiles, BK=64,
// XOR-swizzled LDS (row stride 64 shorts = 32 banks -> conflict-free).
__launch_bounds__(256, 2)
__global__ void qkv_gemm(const short* __restrict__ hbf, const short* __restrict__ pbf,
                         const short* __restrict__ BTq, const short* __restrict__ BTk,
                         const short* __restrict__ BTv,
                         const float* __restrict__ bq, const float* __restrict__ bk,
                         const float* __restrict__ bv,
                         short* __restrict__ outq, short* __restrict__ outk,
                         short* __restrict__ outv,
                         const float* __restrict__ cost, const float* __restrict__ sint) {
  __shared__ __align__(16) short As[128 * 64];
  __shared__ __align__(16) short Bs1[128 * 64];
  __shared__ __align__(16) short Bs2[128 * 64];
  int id = blockIdx.x;
  int xcd = id & 7;
  int local = id >> 3;        // 0..159
  int n0i = local & 7;        // n-block, consecutive per y on one XCD
  int yl = local >> 3;        // 0..19
  int y = yl * 8 + xcd;       // 0..159, y mod 8 == xcd
  int tid = threadIdx.x;
  int lane = tid & 63, wvv = tid >> 6;
  int quad = lane >> 4, c = lane & 15;
  int wm = wvv & 1, wn = wvv >> 1;
  bool isQ = y < 32;
  int m0 = (isQ ? y : (y - 32)) * 128;
  int n0 = n0i * 128;
  const short* A  = isQ ? hbf : pbf;
  const short* B1 = isQ ? BTq : BTk;
  f32x4 acc1[4][4] = {}, acc2[4][4] = {};
  const short* Ab = A + (size_t)m0 * 1024;
  const short* Bb1 = B1 + (size_t)n0 * 1024;
  const short* Bb2 = BTv + (size_t)n0 * 1024;
  int sr = tid >> 3, sch = tid & 7;

  for (int kb = 0; kb < 16; ++kb) {
    int k0 = kb * 64;
    __syncthreads();
#pragma unroll
    for (int rd = 0; rd < 4; ++rd) {
      int row = sr + rd * 32;
      int col = ((sch ^ (row & 7)) * 8) + k0;
      gload_lds16(Ab + row * 1024 + col,  As  + rd * 2048 + tid * 8);
      gload_lds16(Bb1 + row * 1024 + col, Bs1 + rd * 2048 + tid * 8);
      if (!isQ) gload_lds16(Bb2 + row * 1024 + col, Bs2 + rd * 2048 + tid * 8);
    }
    __syncthreads();
#pragma unroll
    for (int ko = 0; ko < 2; ++ko) {
      bf16x8 af[4], b1f[4];
#pragma unroll
      for (int mt = 0; mt < 4; ++mt) {
        int row = wm * 64 + mt * 16 + c;
        af[mt] = *(const bf16x8*)&As[row * 64 + (((ko * 4 + quad) ^ (row & 7)) * 8)];
      }
#pragma unroll
      for (int nt = 0; nt < 4; ++nt) {
        int row = wn * 64 + nt * 16 + c;
        b1f[nt] = *(const bf16x8*)&Bs1[row * 64 + (((ko * 4 + quad) ^ (row & 7)) * 8)];
      }
#pragma unroll
      for (int mt = 0; mt < 4; ++mt)
#pragma unroll
        for (int nt = 0; nt < 4; ++nt)
          acc1[mt][nt] = __builtin_amdgcn_mfma_f32_16x16x32_bf16(af[mt], b1f[nt], acc1[mt][nt], 0, 0, 0);
      if (!isQ) {
        bf16x8 b2f_[4];
#pragma unroll
        for (int nt = 0; nt < 4; ++nt) {
          int row = wn * 64 + nt * 16 + c;
          b2f_[nt] = *(const bf16x8*)&Bs2[row * 64 + (((ko * 4 + quad) ^ (row & 7)) * 8)];
        }
#pragma unroll
        for (int mt = 0; mt < 4; ++mt)
#pragma unroll
          for (int nt = 0; nt < 4; ++nt)
            acc2[mt][nt] = __builtin_amdgcn_mfma_f32_16x16x32_bf16(af[mt], b2f_[nt], acc2[mt][nt], 0, 0, 0);
      }
    }
  }

  int colb = n0 + wn * 64;
  int hh = colb >> 6;
  if (isQ) {
    rope_epilogue(acc1, bq, outq, cost, sint, m0, wm, quad, c, hh);
  } else {
    rope_epilogue(acc1, bk, outk, cost, sint, m0, wm, quad, c, hh);
    float bb[4];
#pragma unroll
    for (int nt = 0; nt < 4; ++nt) bb[nt] = bv[hh * 64 + nt * 16 + c];
#pragma unroll
    for (int mt = 0; mt < 4; ++mt) {
      int gm = m0 + wm * 64 + mt * 16 + quad * 4;
      int s4 = gm & 1023, pb = gm >> 10;
#pragma unroll
      for (int nt = 0; nt < 4; ++nt) {
        int d = nt * 16 + c;
        ushort4 pk;
        pk.x = (unsigned short)f2b(acc2[mt][nt][0] + bb[nt]);
        pk.y = (unsigned short)f2b(acc2[mt][nt][1] + bb[nt]);
        pk.z = (unsigned short)f2b(acc2[mt][nt][2] + bb[nt]);
        pk.w = (unsigned short)f2b(acc2[mt][nt][3] + bb[nt]);
        *(ushort4*)&outv[((pb * NH + hh) * HD + d) * S_ + s4] = pk;
      }
    }
  }
}

// ---------------------------------------------------------------------------
// Flash attention v5: 32x32x16 MFMA, S^T = K*Q^T, P fully in registers
// (cvt_pk_bf16 + permlane32_swap). NEW: double-buffered K/V staging with
// counted vmcnt(4) + raw barriers -- stage(t+1) issues before the wait for
// stage(t), so HBM/L2 latency hides under compute instead of draining at a
// __syncthreads every iteration. LDS 33.3KB, 4 blocks/CU.
__launch_bounds__(256, 4)
__global__ void attn_kernel(const short* __restrict__ q, const short* __restrict__ k,
                            const short* __restrict__ vt, short* __restrict__ o) {
  int blk = blockIdx.x;
  int x = blk & 7, qt = (blk >> 3) & 7, g = blk >> 6;
  int pbh = g * 8 + x;
  int b = (pbh >> 4) & 3, h = pbh & 15;
  int tid = threadIdx.x;
  int w = tid >> 6, lane = tid & 63;
  int l31 = lane & 31, hh = lane >> 5;   // half index (lane>=32)
  int r7 = l31 & 7;

  __shared__ __align__(16) short Klds[2][64 * 64];
  __shared__ __align__(16) short Vlds[2][64 * 64];
  __shared__ float lsumf[4][32];

  // Q fragments (B operand of 32x32x16): lane holds Q[q=l31][hd=step*16+hh*8+j]
  const short* qbase = q + ((size_t)(b * NH + h) * S_ + qt * 128 + w * 32 + l31) * HD + hh * 8;
  bf16x8 aq[4];
#pragma unroll
  for (int st4 = 0; st4 < 4; ++st4) aq[st4] = *(const bf16x8*)(qbase + st4 * 16);

  const short* kb = k + (size_t)pbh * S_ * HD;
  const short* vb = vt + (size_t)pbh * HD * S_;

  f32x16 O0 = {}, O1 = {};
  float ls0 = 0.f, ls1 = 0.f, ls2 = 0.f, ls3 = 0.f;
  const float cs = 0.18033688011f;  // 0.125 * log2(e)

  int sr = tid >> 3;
  int lc = (tid & 7) ^ (sr & 7);

#define STAGE_KV(kt2, bufi) do {                                           \
    const short* ksrc = kb + ((kt2) * 64 + sr) * HD + lc * 8;              \
    gload_lds16(ksrc,           &Klds[bufi][tid * 8]);                     \
    gload_lds16(ksrc + 32 * HD, &Klds[bufi][2048 + tid * 8]);              \
    const short* vsrc = vb + (size_t)sr * S_ + (kt2) * 64 + lc * 8;        \
    gload_lds16(vsrc,           &Vlds[bufi][tid * 8]);                     \
    gload_lds16(vsrc + 32 * S_, &Vlds[bufi][2048 + tid * 8]);              \
  } while (0)

  STAGE_KV(0, 0);

  for (int kt = 0; kt < 16; ++kt) {
    int cb = kt & 1;
    if (kt < 15) {
      STAGE_KV(kt + 1, cb ^ 1);
      asm volatile("s_waitcnt vmcnt(4)" ::: "memory");  // publish stage(kt); 4 in flight
    } else {
      asm volatile("s_waitcnt vmcnt(0)" ::: "memory");
    }
    __builtin_amdgcn_s_barrier();
    __builtin_amdgcn_sched_barrier(0);

    // QK^T: two 32x32 k-tiles; contraction over hd=64 in 4 steps of 16.
    // S^T reg layout: q = l31, k32 = (r&3)+8*(r>>2)+4*hh.
    u32x4 pa[4];
#pragma unroll
    for (int tau = 0; tau < 2; ++tau) {
      f32x16 st = {};
#pragma unroll
      for (int step = 0; step < 4; ++step) {
        bf16x8 kf = *(const bf16x8*)&Klds[cb][(tau * 32 + l31) * 64 + (((step * 2 + hh) ^ r7) * 8)];
        st = __builtin_amdgcn_mfma_f32_32x32x16_bf16(kf, aq[step], st, 0, 0, 0);
      }
      unsigned wb[8];
#pragma unroll
      for (int m = 0; m < 8; ++m) {
        float p0 = fast_exp2(st[2 * m] * cs);
        float p1 = fast_exp2(st[2 * m + 1] * cs);
        float ps = p0 + p1;
        if ((m & 3) == 0) ls0 += ps;
        else if ((m & 3) == 1) ls1 += ps;
        else if ((m & 3) == 2) ls2 += ps;
        else ls3 += ps;
        asm("v_cvt_pk_bf16_f32 %0, %1, %2" : "=v"(wb[m]) : "v"(p0), "v"(p1));
      }
#pragma unroll
      for (int gg = 0; gg < 2; ++gg) {
        unsigned x0 = wb[4 * gg + 0], y0 = wb[4 * gg + 2];
        unsigned x1 = wb[4 * gg + 1], y1 = wb[4 * gg + 3];
        asm volatile("v_permlane32_swap_b32 %0, %1" : "+v"(x0), "+v"(y0));
        asm volatile("v_permlane32_swap_b32 %0, %1" : "+v"(x1), "+v"(y1));
        u32x4 paw;
        paw[0] = x0; paw[1] = x1; paw[2] = y0; paw[3] = y1;
        pa[2 * tau + gg] = paw;
      }
    }

    // PV: O[q][d], two 32-wide d-tiles, contraction k=64 in 4 steps of 16.
#pragma unroll
    for (int T = 0; T < 4; ++T) {
      bf16x8 ap = __builtin_bit_cast(bf16x8, pa[T]);
      bf16x8 vf0 = *(const bf16x8*)&Vlds[cb][l31 * 64 + (((T * 2 + hh) ^ r7) * 8)];
      O0 = __builtin_amdgcn_mfma_f32_32x32x16_bf16(ap, vf0, O0, 0, 0, 0);
      bf16x8 vf1 = *(const bf16x8*)&Vlds[cb][(32 + l31) * 64 + (((T * 2 + hh) ^ r7) * 8)];
      O1 = __builtin_amdgcn_mfma_f32_32x32x16_bf16(ap, vf1, O1, 0, 0, 0);
    }

    __builtin_amdgcn_s_barrier();  // consume-done: next iter may overwrite buf^1
  }
#undef STAGE_KV

  float lsum = (ls0 + ls1) + (ls2 + ls3);
  lsum += __shfl_xor(lsum, 32, 64);
  if (lane < 32) lsumf[w][l31] = lsum;

  short* ob = o + ((size_t)pbh * S_ + qt * 128 + w * 32) * HD;
#pragma unroll
  for (int gg = 0; gg < 4; ++gg) {
    f32x4 lv = *(const f32x4*)&lsumf[w][4 * hh + 8 * gg];
#pragma unroll
    for (int j = 0; j < 4; ++j) {
      float inv = 1.0f / lv[j];
      int qrow = 4 * hh + 8 * gg + j;
      ob[qrow * HD + l31]      = f2b(O0[4 * gg + j] * inv);
      ob[qrow * HD + 32 + l31] = f2b(O1[4 * gg + j] * inv);
    }
  }
}

// ---------------------------------------------------------------------------
__global__ void combine_kernel(const short* __restrict__ o, const float* __restrict__ lw,
                               short* __restrict__ comb) {
  int idx = blockIdx.x * 256 + threadIdx.x;
  int e8 = idx & 127;
  int s = (idx >> 7) & 1023;
  int b = idx >> 17;
  int h = e8 >> 3, d0 = (e8 & 7) * 8;
  float acc[8] = {};
#pragma unroll
  for (int p = 0; p < 4; ++p) {
    float wgt = lw[p * 4 + b];  // faithful transposed broadcast: LW[p][b]
    const short* op = o + (((size_t)(p * 4 + b) * NH + h) * S_ + s) * HD + d0;
    bf16x8 v = *(const bf16x8*)op;
#pragma unroll
    for (int i = 0; i < 8; ++i) acc[i] += wgt * b2f(v[i]);
  }
  bf16x8 pk;
#pragma unroll
  for (int i = 0; i < 8; ++i) pk[i] = f2b(acc[i]);
  *(bf16x8*)&comb[((size_t)b * S_ + s) * H_ + e8 * 8] = pk;
}

// ---------------------------------------------------------------------------
// Final projection: C[4096,1024] fp32 = comb @ woT + bo. 64x128 tiles, BK=64,
// swizzled LDS, XCD-coherent decode. grid 512 linear, (256,4).
__launch_bounds__(256, 4)
__global__ void gemm_out(const short* __restrict__ A, const short* __restrict__ BT,
                         const float* __restrict__ bias, float* __restrict__ outf) {
  __shared__ __align__(16) short As[64 * 64];
  __shared__ __align__(16) short Bs[128 * 64];
  int id = blockIdx.x;
  int xcd = id & 7;
  int local = id >> 3;        // 0..63
  int n0i = local & 7;
  int yl = local >> 3;        // 0..7
  int y = yl * 8 + xcd;       // 0..63
  int tid = threadIdx.x;
  int lane = tid & 63, wvv = tid >> 6;
  int quad = lane >> 4, c = lane & 15;
  int wm = wvv & 1, wn = wvv >> 1;
  int m0 = y * 64, n0 = n0i * 128;
  f32x4 acc[2][4] = {};
  const short* Ab = A + (size_t)m0 * 1024;
  const short* Bb = BT + (size_t)n0 * 1024;
  int sr = tid >> 3, sch = tid & 7;

  for (int kb = 0; kb < 16; ++kb) {
    int k0 = kb * 64;
    __syncthreads();
#pragma unroll
    for (int rd = 0; rd < 2; ++rd) {
      int row = sr + rd * 32;
      int col = ((sch ^ (row & 7)) * 8) + k0;
      gload_lds16(Ab + row * 1024 + col, As + rd * 2048 + tid * 8);
    }
#pragma unroll
    for (int rd = 0; rd < 4; ++rd) {
      int row = sr + rd * 32;
      int col = ((sch ^ (row & 7)) * 8) + k0;
      gload_lds16(Bb + row * 1024 + col, Bs + rd * 2048 + tid * 8);
    }
    __syncthreads();
#pragma unroll
    for (int ko = 0; ko < 2; ++ko) {
      bf16x8 af[2], bfr[4];
#pragma unroll
      for (int mt = 0; mt < 2; ++mt) {
        int row = wm * 32 + mt * 16 + c;
        af[mt] = *(const bf16x8*)&As[row * 64 + (((ko * 4 + quad) ^ (row & 7)) * 8)];
      }
#pragma unroll
      for (int nt = 0; nt < 4; ++nt) {
        int row = wn * 64 + nt * 16 + c;
        bfr[nt] = *(const bf16x8*)&Bs[row * 64 + (((ko * 4 + quad) ^ (row & 7)) * 8)];
      }
#pragma unroll
      for (int mt = 0; mt < 2; ++mt)
#pragma unroll
        for (int nt = 0; nt < 4; ++nt)
          acc[mt][nt] = __builtin_amdgcn_mfma_f32_16x16x32_bf16(af[mt], bfr[nt], acc[mt][nt], 0, 0, 0);
    }
  }

  int colb = n0 + wn * 64;
  float bb[4];
#pragma unroll
  for (int nt = 0; nt < 4; ++nt) bb[nt] = bias[colb + nt * 16 + c];
#pragma unroll
  for (int mt = 0; mt < 2; ++mt) {
    int gm = m0 + wm * 32 + mt * 16 + quad * 4;
#pragma unroll
    for (int j = 0; j < 4; ++j) {
      int m = gm + j;
#pragma unroll
      for (int nt = 0; nt < 4; ++nt)
        outf[(size_t)m * 1024 + colb + nt * 16 + c] = acc[mt][nt][j] + bb[nt];
    }
  }
}

// ---------------------------------------------------------------------------
extern "C" void kernel_launch(void* const* d_in, const int* in_sizes, int n_in,
                              void* d_out, int out_size, void* d_ws, size_t ws_size,
                              hipStream_t stream) {
  (void)in_sizes; (void)n_in; (void)out_size; (void)ws_size;
  const float* hidden = (const float*)d_in[0];
  const float* prev   = (const float*)d_in[1];
  const float* wq = (const float*)d_in[2];
  const float* bq = (const float*)d_in[3];
  const float* wk = (const float*)d_in[4];
  const float* bk = (const float*)d_in[5];
  const float* wv = (const float*)d_in[6];
  const float* bv = (const float*)d_in[7];
  const float* wo = (const float*)d_in[8];
  const float* bo = (const float*)d_in[9];
  const float* wg = (const float*)d_in[10];
  float* out = (float*)d_out;
  char* ws = (char*)d_ws;

  size_t off = 0;
  short* wqT = (short*)(ws + off); off += (size_t)1024 * 1024 * 2;
  short* wkT = (short*)(ws + off); off += (size_t)1024 * 1024 * 2;
  short* wvT = (short*)(ws + off); off += (size_t)1024 * 1024 * 2;
  short* woT = (short*)(ws + off); off += (size_t)1024 * 1024 * 2;
  short* hbf = (short*)(ws + off); off += (size_t)B_ * S_ * H_ * 2;
  short* pbf = (short*)(ws + off); off += (size_t)P_ * B_ * S_ * H_ * 2;
  short* qbf = (short*)(ws + off); off += (size_t)B_ * S_ * H_ * 2;
  short* kbf = (short*)(ws + off); off += (size_t)P_ * B_ * S_ * H_ * 2;
  short* vtb = (short*)(ws + off); off += (size_t)P_ * B_ * S_ * H_ * 2;
  float* cost = (float*)(ws + off); off += (size_t)S_ * 32 * 4;
  float* sint = (float*)(ws + off); off += (size_t)S_ * 32 * 4;
  float* pooled = (float*)(ws + off); off += (size_t)B_ * 32 * 1024 * 4;
  float* lw = (float*)(ws + off); off += 64;
  short* obf  = pbf;  // alias: pbf dead after QKV proj
  short* comb = qbf;  // alias: qbf dead after attention

  prep_kernel<<<14592, 256, 0, stream>>>(hidden, prev, wq, wk, wv, wo,
                                         hbf, pbf, wqT, wkT, wvT, woT,
                                         cost, sint, pooled);
  gate_kernel<<<1, 256, 0, stream>>>(pooled, wg, lw);
  qkv_gemm<<<1280, 256, 0, stream>>>(hbf, pbf, wqT, wkT, wvT,
                                     bq, bk, bv, qbf, kbf, vtb, cost, sint);
  attn_kernel<<<2048, 256, 0, stream>>>(qbf, kbf, vtb, obf);
  combine_kernel<<<2048, 256, 0, stream>>>(obf, lw, comb);
  gemm_out<<<512, 256, 0, stream>>>(comb, woT, bo, out);
}